// Round 10
// baseline (1828.523 us; speedup 1.0000x reference)
//
#include <hip/hip_runtime.h>
#include <math.h>

#define TS 43      // tokens per sample (1 + 6*7)
#define DD 128
#define NH 4
#define DFFN 512
#define NLAY 4
#define NT_THREADS 512

typedef __bf16 bf16x8_t __attribute__((ext_vector_type(8)));
typedef float  f32x4_t  __attribute__((ext_vector_type(4)));

#define MFMA16(a, b, c) __builtin_amdgcn_mfma_f32_16x16x32_bf16((a), (b), (c), 0, 0, 0)

// LDS: 74,496 B -> 2 blocks/CU. P[h] (48x72 bf16, 6912B each) overlays QK
// (wave-private after qa/kb are in registers); attn-out reuses QK[0] after PV.
struct __align__(16) SmemT {
  __bf16 xb[48][136];            // residual stream (bf16 storage, f32 math)
  __bf16 yb[48][136];            // LN output (MFMA A input)
  union {
    struct { __bf16 QK[2][48][136]; __bf16 pad[768]; __bf16 Vt[128][72]; } a;
    struct { __bf16 gbuf[48][264]; } f;   // FFN intermediate (half of 512)
  } u;
  float bias[NH][144];
};

__device__ __forceinline__ float wsum(float v) {
  #pragma unroll
  for (int m = 32; m >= 1; m >>= 1) v += __shfl_xor(v, m, 64);
  return v;
}
__device__ __forceinline__ float red16max(float v) {
  #pragma unroll
  for (int m = 8; m >= 1; m >>= 1) v = fmaxf(v, __shfl_xor(v, m, 64));
  return v;
}
__device__ __forceinline__ float red16sum(float v) {
  #pragma unroll
  for (int m = 8; m >= 1; m >>= 1) v += __shfl_xor(v, m, 64);
  return v;
}
__device__ __forceinline__ float gelu_exact(float x) {
  return 0.5f * x * (1.0f + erff(x * 0.70710678118654752f));
}

// ---- weight prep: f32 [K][N] -> bf16 W^T [N][K] in d_ws ----
__global__ void prep_weights(const float* __restrict__ Wq, const float* __restrict__ Wk,
                             const float* __restrict__ Wv, const float* __restrict__ Wo,
                             const float* __restrict__ W1, const float* __restrict__ W2,
                             __bf16* __restrict__ ws) {
  int idx = blockIdx.x * 256 + threadIdx.x;
  if (idx < 262144) {
    int t = idx >> 16;            // 0..3 : q,k,v,o
    int rem = idx & 65535;
    int l = rem >> 14;
    int r2 = rem & 16383;
    int n = r2 >> 7, k = r2 & 127;
    const float* W = (t == 0) ? Wq : (t == 1) ? Wk : (t == 2) ? Wv : Wo;
    ws[idx] = (__bf16)W[l * 16384 + k * 128 + n];
  } else if (idx < 524288) {
    int rem = idx - 262144;       // W1T: [512][128] per layer
    int l = rem >> 16;
    int r2 = rem & 65535;
    int n = r2 >> 7, k = r2 & 127;
    ws[idx] = (__bf16)W1[l * 65536 + k * 512 + n];
  } else if (idx < 786432) {
    int rem = idx - 524288;       // W2T: [128][512] per layer
    int l = rem >> 16;
    int r2 = rem & 65535;
    int n = r2 >> 9, f = r2 & 511;
    ws[idx] = (__bf16)W2[l * 65536 + f * 128 + n];
  }
}

__global__ __launch_bounds__(NT_THREADS, 4)
void tdqn_fused(const int* __restrict__ board, const int* __restrict__ ptm_arr,
                const int* __restrict__ bucket_index,
                const float* __restrict__ cell_emb, const float* __restrict__ player_emb,
                const float* __restrict__ cls_token, const float* __restrict__ bias_table,
                const float* __restrict__ ln1_s, const float* __restrict__ ln1_b,
                const float* __restrict__ bq, const float* __restrict__ bk,
                const float* __restrict__ bv, const float* __restrict__ bo,
                const float* __restrict__ ln2_s, const float* __restrict__ ln2_b,
                const float* __restrict__ b1, const float* __restrict__ b2,
                const float* __restrict__ lnf_s, const float* __restrict__ lnf_b,
                const float* __restrict__ Whead, const float* __restrict__ bhead,
                const __bf16* __restrict__ ws,
                float* __restrict__ out, int nB)
{
  __shared__ SmemT sm;
  const int b = blockIdx.x;
  const int tid = threadIdx.x;
  const int lane = tid & 63;
  const int wave = tid >> 6;         // 0..7
  const int l15 = lane & 15;
  const int hi8 = (lane >> 4) * 8;   // k-offset within fragment
  const int hi4 = (lane >> 4) * 4;   // row-offset within D tile

  // ---- stage bias table ----
  for (int idx = tid; idx < NH * 143; idx += NT_THREADS)
    sm.bias[idx / 143][idx % 143] = bias_table[idx];

  // ---- embeddings -> bf16 residual ----
  const int ptm = ptm_arr[b];
  for (int idx = tid; idx < TS * DD; idx += NT_THREADS) {
    int t = idx >> 7, d = idx & 127;
    float v;
    if (t == 0) v = cls_token[d] + player_emb[ptm * DD + d];
    else        v = cell_emb[board[b * 42 + (t - 1)] * DD + d];
    sm.xb[t][d] = (__bf16)v;
  }
  __syncthreads();

  // LN (f32 stats from bf16 xb) -> yb bf16
  auto layer_norm = [&](const float* s, const float* bb) {
    for (int t = wave; t < TS; t += 8) {
      float a0 = (float)sm.xb[t][lane], a1 = (float)sm.xb[t][lane + 64];
      float sum = wsum(a0 + a1);
      float sq  = wsum(a0 * a0 + a1 * a1);
      float mu  = sum * (1.0f / 128.0f);
      float var = sq * (1.0f / 128.0f) - mu * mu;
      float r   = rsqrtf(var + 1e-5f);
      sm.yb[t][lane]      = (__bf16)((a0 - mu) * r * s[lane]      + bb[lane]);
      sm.yb[t][lane + 64] = (__bf16)((a1 - mu) * r * s[lane + 64] + bb[lane + 64]);
    }
    // zero pad rows 43..47 (feed MFMA A-frags)
    for (int idx = tid; idx < 5 * 136; idx += NT_THREADS)
      sm.yb[43 + idx / 136][idx % 136] = (__bf16)0.f;
  };

  // 48x128 @ 128x16 tile: af rows from LDS, B-frags from global W^T row nrow
  auto gemmNT1 = [&](const bf16x8_t (&af)[3][4], const __bf16* WT, int nrow,
                     f32x4_t (&acc)[3]) {
    #pragma unroll
    for (int kk = 0; kk < 4; ++kk) {
      bf16x8_t bfrag = *(const bf16x8_t*)(WT + nrow * DD + kk * 32 + hi8);
      #pragma unroll
      for (int m = 0; m < 3; ++m)
        acc[m] = MFMA16(af[m][kk], bfrag, acc[m]);
    }
  };

  for (int l = 0; l < NLAY; ++l) {
    const __bf16* WqT = ws + l * 16384;
    const __bf16* WkT = ws + 65536  + l * 16384;
    const __bf16* WvT = ws + 131072 + l * 16384;
    const __bf16* WoT = ws + 196608 + l * 16384;
    const __bf16* W1T = ws + 262144 + l * 65536;
    const __bf16* W2T = ws + 524288 + l * 65536;
    const float* bq_l = bq + l * DD;
    const float* bk_l = bk + l * DD;
    const float* bv_l = bv + l * DD;
    const float* bo_l = bo + l * DD;
    const float* b1_l = b1 + l * DFFN;
    const float* b2_l = b2 + l * DD;

    // ---- LN1 (+ zero Vt token-pad cols 48..71) ----
    layer_norm(ln1_s + l * DD, ln1_b + l * DD);
    for (int idx = tid; idx < 128 * 3; idx += NT_THREADS) {
      bf16x8_t z = {};
      *(bf16x8_t*)(&sm.u.a.Vt[idx / 3][48 + (idx % 3) * 8]) = z;
    }
    __syncthreads();

    // ---- QKV projections: each wave owns 16 output cols ----
    {
      bf16x8_t af[3][4];
      #pragma unroll
      for (int m = 0; m < 3; ++m) {
        #pragma unroll
        for (int kk = 0; kk < 4; ++kk)
          af[m][kk] = *(const bf16x8_t*)(&sm.yb[m * 16 + l15][kk * 32 + hi8]);
      }
      const int nrow = wave * 16 + l15;
      const int col  = nrow;

      { // Q
        f32x4_t acc[3] = {};
        gemmNT1(af, WqT, nrow, acc);
        float bvv = bq_l[col];
        #pragma unroll
        for (int m = 0; m < 3; ++m) {
          #pragma unroll
          for (int r = 0; r < 4; ++r)
            sm.u.a.QK[0][m * 16 + hi4 + r][col] = (__bf16)(acc[m][r] + bvv);
        }
      }
      { // K
        f32x4_t acc[3] = {};
        gemmNT1(af, WkT, nrow, acc);
        float bvv = bk_l[col];
        #pragma unroll
        for (int m = 0; m < 3; ++m) {
          #pragma unroll
          for (int r = 0; r < 4; ++r)
            sm.u.a.QK[1][m * 16 + hi4 + r][col] = (__bf16)(acc[m][r] + bvv);
        }
      }
      { // V -> transposed store Vt[d][token]
        f32x4_t acc[3] = {};
        gemmNT1(af, WvT, nrow, acc);
        float bvv = bv_l[col];
        #pragma unroll
        for (int m = 0; m < 3; ++m) {
          #pragma unroll
          for (int r = 0; r < 4; ++r)
            sm.u.a.Vt[col][m * 16 + hi4 + r] = (__bf16)(acc[m][r] + bvv);
        }
      }
    }
    __syncthreads();

    // ---- attention: waves 0..3 (one head each); P overlays QK region ----
    {
      const int h = wave;
      __bf16* P_h = &sm.u.a.QK[0][0][0] + h * 3456;   // [48][72] per head
      bf16x8_t qa[3], kb[3];
      f32x4_t oacc[3][2] = {};

      if (wave < NH) {
        #pragma unroll
        for (int m = 0; m < 3; ++m)
          qa[m] = *(const bf16x8_t*)(&sm.u.a.QK[0][m * 16 + l15][h * 32 + hi8]);
        #pragma unroll
        for (int nt = 0; nt < 3; ++nt)
          kb[nt] = *(const bf16x8_t*)(&sm.u.a.QK[1][nt * 16 + l15][h * 32 + hi8]);
      }
      __syncthreads();   // all QK reads done before P overlay writes

      if (wave < NH) {
        f32x4_t sc[3][3] = {};
        #pragma unroll
        for (int m = 0; m < 3; ++m) {
          #pragma unroll
          for (int nt = 0; nt < 3; ++nt)
            sc[m][nt] = MFMA16(qa[m], kb[nt], sc[m][nt]);
        }

        const float scl = 0.17677669529663687f;  // 1/sqrt(32)
        float ev[3][3][4];
        float lmax[3][4], lsum[3][4];
        #pragma unroll
        for (int m = 0; m < 3; ++m) {
          #pragma unroll
          for (int r = 0; r < 4; ++r) lmax[m][r] = -1e30f;
        }
        #pragma unroll
        for (int nt = 0; nt < 3; ++nt) {
          const int k = nt * 16 + l15;
          const bool kval = (k <= 42);
          const unsigned km = (k >= 1) ? (unsigned)(k - 1) : 0u;
          const int rk = (int)(km / 7u);
          const int ck = (int)(km - rk * 7u);
          #pragma unroll
          for (int m = 0; m < 3; ++m) {
            #pragma unroll
            for (int r = 0; r < 4; ++r) {
              int q = m * 16 + hi4 + r;
              int qv = q > 42 ? 42 : q;
              float v;
              if (kval) {
                int idx;
                if (qv == 0 || k == 0) idx = 0;
                else {
                  unsigned qm = (unsigned)(qv - 1);
                  int rq = (int)(qm / 7u);
                  int cq = (int)(qm - rq * 7u);
                  idx = (rq - rk) * 13 + (cq - ck) + 71;  // (dr+5)*13 + dc+6
                }
                v = sc[m][nt][r] * scl + sm.bias[h][idx];
              } else v = -1e30f;
              ev[m][nt][r] = v;
              lmax[m][r] = fmaxf(lmax[m][r], v);
            }
          }
        }
        #pragma unroll
        for (int m = 0; m < 3; ++m) {
          #pragma unroll
          for (int r = 0; r < 4; ++r) {
            lmax[m][r] = red16max(lmax[m][r]);
            lsum[m][r] = 0.f;
          }
        }
        #pragma unroll
        for (int m = 0; m < 3; ++m) {
          #pragma unroll
          for (int nt = 0; nt < 3; ++nt) {
            const int k = nt * 16 + l15;
            #pragma unroll
            for (int r = 0; r < 4; ++r) {
              float e = (k <= 42) ? expf(ev[m][nt][r] - lmax[m][r]) : 0.f;
              ev[m][nt][r] = e;
              lsum[m][r] += e;
            }
          }
        }
        #pragma unroll
        for (int m = 0; m < 3; ++m) {
          #pragma unroll
          for (int r = 0; r < 4; ++r)
            lsum[m][r] = 1.0f / red16sum(lsum[m][r]);
        }
        // write P (wave-private overlay of QK region)
        #pragma unroll
        for (int m = 0; m < 3; ++m) {
          #pragma unroll
          for (int nt = 0; nt < 3; ++nt) {
            #pragma unroll
            for (int r = 0; r < 4; ++r)
              P_h[(m * 16 + hi4 + r) * 72 + nt * 16 + l15] =
                  (__bf16)(ev[m][nt][r] * lsum[m][r]);
          }
        }
        // zero P key-cols 48..63
        for (int i = lane; i < 96; i += 64) {
          bf16x8_t z = {};
          *(bf16x8_t*)(P_h + (i >> 1) * 72 + 48 + (i & 1) * 8) = z;
        }
        // PV (same wave: no barrier; compiler orders via lgkmcnt)
        #pragma unroll
        for (int ks = 0; ks < 2; ++ks) {
          bf16x8_t pa[3], vb[2];
          #pragma unroll
          for (int m = 0; m < 3; ++m)
            pa[m] = *(const bf16x8_t*)(P_h + (m * 16 + l15) * 72 + ks * 32 + hi8);
          #pragma unroll
          for (int nt = 0; nt < 2; ++nt)
            vb[nt] = *(const bf16x8_t*)(&sm.u.a.Vt[h * 32 + nt * 16 + l15][ks * 32 + hi8]);
          #pragma unroll
          for (int m = 0; m < 3; ++m) {
            #pragma unroll
            for (int nt = 0; nt < 2; ++nt)
              oacc[m][nt] = MFMA16(pa[m], vb[nt], oacc[m][nt]);
          }
        }
      }
      __syncthreads();   // all P reads done before attn-out overlay

      if (wave < NH) {   // attn-out -> QK[0] slot
        #pragma unroll
        for (int nt = 0; nt < 2; ++nt) {
          int col = h * 32 + nt * 16 + l15;
          #pragma unroll
          for (int m = 0; m < 3; ++m) {
            #pragma unroll
            for (int r = 0; r < 4; ++r)
              sm.u.a.QK[0][m * 16 + hi4 + r][col] = (__bf16)(oacc[m][nt][r]);
          }
        }
      }
      __syncthreads();
    }

    // ---- O projection + residual into xb ----
    {
      bf16x8_t af[3][4];
      #pragma unroll
      for (int m = 0; m < 3; ++m) {
        #pragma unroll
        for (int kk = 0; kk < 4; ++kk)
          af[m][kk] = *(const bf16x8_t*)(&sm.u.a.QK[0][m * 16 + l15][kk * 32 + hi8]);
      }
      f32x4_t acc[3] = {};
      const int nrow = wave * 16 + l15;
      gemmNT1(af, WoT, nrow, acc);
      const int col = nrow;
      float bvv = bo_l[col];
      #pragma unroll
      for (int m = 0; m < 3; ++m) {
        #pragma unroll
        for (int r = 0; r < 4; ++r) {
          int row = m * 16 + hi4 + r;
          if (row < TS)
            sm.xb[row][col] = (__bf16)((float)sm.xb[row][col] + acc[m][r] + bvv);
        }
      }
    }
    __syncthreads();

    // ---- LN2 ----
    layer_norm(ln2_s + l * DD, ln2_b + l * DD);
    __syncthreads();

    // ---- FFN in two 256-col halves; B-accumulator lives in registers ----
    {
      bf16x8_t af[3][4];
      #pragma unroll
      for (int m = 0; m < 3; ++m) {
        #pragma unroll
        for (int kk = 0; kk < 4; ++kk)
          af[m][kk] = *(const bf16x8_t*)(&sm.yb[m * 16 + l15][kk * 32 + hi8]);
      }
      f32x4_t bacc[3] = {};
      const int nrow2 = wave * 16 + l15;   // FFN-B output col

      #pragma unroll
      for (int half = 0; half < 2; ++half) {
        // A: gbuf = gelu(yb @ W1half + b1); wave owns 32 local cols
        #pragma unroll
        for (int cc = 0; cc < 2; ++cc) {
          f32x4_t acc[3] = {};
          const int ncol = half * 256 + wave * 32 + cc * 16 + l15;  // global
          gemmNT1(af, W1T, ncol, acc);
          const int lcol = wave * 32 + cc * 16 + l15;               // local
          float bvv = b1_l[ncol];
          #pragma unroll
          for (int m = 0; m < 3; ++m) {
            #pragma unroll
            for (int r = 0; r < 4; ++r)
              sm.u.f.gbuf[m * 16 + hi4 + r][lcol] = (__bf16)gelu_exact(acc[m][r] + bvv);
          }
        }
        __syncthreads();
        // B: accumulate this half's 256 k-values
        for (int ksl = 0; ksl < 8; ++ksl) {
          bf16x8_t ga[3], wb;
          #pragma unroll
          for (int m = 0; m < 3; ++m)
            ga[m] = *(const bf16x8_t*)(&sm.u.f.gbuf[m * 16 + l15][ksl * 32 + hi8]);
          wb = *(const bf16x8_t*)(W2T + nrow2 * DFFN + (half * 8 + ksl) * 32 + hi8);
          #pragma unroll
          for (int m = 0; m < 3; ++m)
            bacc[m] = MFMA16(ga[m], wb, bacc[m]);
        }
        __syncthreads();   // before next half overwrites gbuf / next phase
      }

      const int col = nrow2;
      float bvv = b2_l[col];
      #pragma unroll
      for (int m = 0; m < 3; ++m) {
        #pragma unroll
        for (int r = 0; r < 4; ++r) {
          int row = m * 16 + hi4 + r;
          if (row < TS)
            sm.xb[row][col] = (__bf16)((float)sm.xb[row][col] + bacc[m][r] + bvv);
        }
      }
    }
    __syncthreads();
  }

  // ---- final LN (token 0) -> yb[0] bf16 ----
  if (wave == 0) {
    float a0 = (float)sm.xb[0][lane], a1 = (float)sm.xb[0][lane + 64];
    float sum = wsum(a0 + a1);
    float sq  = wsum(a0 * a0 + a1 * a1);
    float mu  = sum * (1.0f / 128.0f);
    float var = sq * (1.0f / 128.0f) - mu * mu;
    float r   = rsqrtf(var + 1e-5f);
    sm.yb[0][lane]      = (__bf16)((a0 - mu) * r * lnf_s[lane]      + lnf_b[lane]);
    sm.yb[0][lane + 64] = (__bf16)((a1 - mu) * r * lnf_s[lane + 64] + lnf_b[lane + 64]);
  }
  __syncthreads();

  // ---- head + masking ----
  if (tid < 7) {
    const int c = tid;
    float acc = bhead[c];
    for (int d = 0; d < DD; ++d) acc += (float)sm.yb[0][d] * Whead[d * 7 + c];
    const int ob = b * 7 + c;
    const bool valid = (board[b * 42 + c] == 0);  // board row 0
    out[ob] = acc;
    out[nB * 7 + ob] = valid ? acc : -1e9f;
    out[2 * nB * 7 + ob] = valid ? 1.0f : 0.0f;
  }
}

extern "C" void kernel_launch(void* const* d_in, const int* in_sizes, int n_in,
                              void* d_out, int out_size, void* d_ws, size_t ws_size,
                              hipStream_t stream) {
  const int*   board      = (const int*)d_in[0];
  const int*   ptm        = (const int*)d_in[1];
  const int*   bucket_idx = (const int*)d_in[2];
  const float* cell_emb   = (const float*)d_in[3];
  const float* player_emb = (const float*)d_in[4];
  const float* cls_token  = (const float*)d_in[5];
  const float* bias_table = (const float*)d_in[6];
  const float* ln1_s      = (const float*)d_in[7];
  const float* ln1_b      = (const float*)d_in[8];
  const float* Wq         = (const float*)d_in[9];
  const float* bq         = (const float*)d_in[10];
  const float* Wk         = (const float*)d_in[11];
  const float* bk         = (const float*)d_in[12];
  const float* Wv         = (const float*)d_in[13];
  const float* bv         = (const float*)d_in[14];
  const float* Wo         = (const float*)d_in[15];
  const float* bo         = (const float*)d_in[16];
  const float* ln2_s      = (const float*)d_in[17];
  const float* ln2_b      = (const float*)d_in[18];
  const float* W1         = (const float*)d_in[19];
  const float* b1         = (const float*)d_in[20];
  const float* W2         = (const float*)d_in[21];
  const float* b2         = (const float*)d_in[22];
  const float* lnf_s      = (const float*)d_in[23];
  const float* lnf_b      = (const float*)d_in[24];
  const float* Whead      = (const float*)d_in[25];
  const float* bhead      = (const float*)d_in[26];

  const int nB = in_sizes[1];  // 4096
  float* out = (float*)d_out;
  __bf16* ws = (__bf16*)d_ws;  // needs 786432*2 = 1.57 MB

  hipLaunchKernelGGL(prep_weights, dim3(3072), dim3(256), 0, stream,
                     Wq, Wk, Wv, Wo, W1, W2, ws);
  hipLaunchKernelGGL(tdqn_fused, dim3(nB), dim3(NT_THREADS), 0, stream,
                     board, ptm, bucket_idx, cell_emb, player_emb, cls_token,
                     bias_table, ln1_s, ln1_b, bq, bk, bv, bo,
                     ln2_s, ln2_b, b1, b2, lnf_s, lnf_b, Whead, bhead,
                     ws, out, nB);
}